// Round 2
// baseline (647.559 us; speedup 1.0000x reference)
//
#include <hip/hip_runtime.h>
#include <hip/hip_bf16.h>
#include <math.h>

#define NQ 4096
#define NK 4096
#define QD 256
#define KD 320
#define HID 256
#define NH 8
#define DH 32
#define NB 16
#define LN_EPS 1e-5f
#define ATT_SCALE 0.17677669529663687f   // 1/sqrt(32)

// ---------------------------------------------------------------------------
// ws layout (float offsets) — ~29.6 MB total
// ---------------------------------------------------------------------------
#define OFF_Q2     0
#define OFF_K2     1048576
#define OFF_V2     2097152
#define OFF_CTX    3145728
#define OFF_WEFFQ  4194304
#define OFF_WEFFK  4259840
#define OFF_WEFFV  4341760
#define OFF_WEFFO  4423680
#define OFF_BEFFQ  4489216
#define OFF_BEFFK  4489472
#define OFF_BEFFV  4489728
#define OFF_BEFFO  4489984
#define OFF_KST    4490240   // 16 ints
#define OFF_KEN    4490256   // 16 ints (as float slots: int* at KST, +16)
#define OFF_FLAG   4490272   // 1 int
#define OFF_QNF    4490304
#define OFF_KNF    5538880
#define OFF_WQF    6849600
#define OFF_BQF    6915136
#define OFF_WKF    6915392
#define OFF_BKF    6997312
#define OFF_WVF    6997568
#define OFF_BVF    7079488
#define OFF_WINF   7079744
#define OFF_BINPF  7276352
#define OFF_MOWF   7277120
#define OFF_MOBF   7342656
#define OFF_WOF    7342912
#define OFF_BOF    7408448
#define OFF_LNGF   7408704
#define OFF_LNBF   7408960
// end 7409216 floats

__device__ __forceinline__ float bf16_bits_to_f(unsigned short s) {
    unsigned int u = (unsigned int)s << 16;
    float f;
    __builtin_memcpy(&f, &u, 4);
    return f;
}

// Probe: decide whether float tensors are bf16 (flag=1) or f32 (flag=0).
// Reads only the first 4096 uint16 (8 KB) of query_nodes — in-bounds under
// both interpretations. bf16 N(0,1) data: max|x| ~ 4. f32 data misread as
// bf16: half the elements are mantissa-half garbage, max|x| >> 100 w.p. ~1.
__global__ void k_detect(const unsigned short* __restrict__ probe,
                         int* __restrict__ flag) {
    __shared__ float red[4];
    int t = threadIdx.x;
    float mx = 0.f;
    for (int i = t; i < 4096; i += 256) {
        float f = fabsf(bf16_bits_to_f(probe[i]));
        if (!(f == f)) f = 1e38f;  // NaN -> huge
        mx = fmaxf(mx, f);
    }
    for (int off = 32; off; off >>= 1) mx = fmaxf(mx, __shfl_xor(mx, off, 64));
    if ((t & 63) == 0) red[t >> 6] = mx;
    __syncthreads();
    if (t == 0) {
        mx = fmaxf(fmaxf(red[0], red[1]), fmaxf(red[2], red[3]));
        *flag = (mx < 100.f) ? 1 : 0;
    }
}

// Convert one input tensor to f32 per flag.
__global__ void k_cvt(const void* __restrict__ src, float* __restrict__ dst,
                      int n, const int* __restrict__ flag) {
    int i = blockIdx.x * 256 + threadIdx.x;
    if (i >= n) return;
    if (*flag)
        dst[i] = bf16_bits_to_f(((const unsigned short*)src)[i]);
    else
        dst[i] = ((const float*)src)[i];
}

__global__ void k_ranges(const int* __restrict__ kb, int* __restrict__ kstart,
                         int* __restrict__ kend) {
    int t = threadIdx.x;
    if (t < NB) { kstart[t] = NK; kend[t] = 0; }
    __syncthreads();
    for (int j = t; j < NK; j += 256) {
        int b = kb[j];
        atomicMin(&kstart[b], j);
        atomicMax(&kend[b], j + 1);
    }
}

// WeffX[i][j] = sum_k A[i][k] * Win[(off+j)][k]   (A row length = HID)
__global__ void k_fuse_qkv(const float* __restrict__ Wq,
                           const float* __restrict__ Wk,
                           const float* __restrict__ Wv,
                           const float* __restrict__ Win,
                           float* __restrict__ WeffQ, float* __restrict__ WeffK,
                           float* __restrict__ WeffV) {
    __shared__ float arow[HID];
    int bid = blockIdx.x;
    const float* A; float* Out; int off;
    if (bid < QD)            { A = Wq; Out = WeffQ; off = 0; }
    else if (bid < QD + KD)  { A = Wk; Out = WeffK; off = HID;   bid -= QD; }
    else                     { A = Wv; Out = WeffV; off = 2*HID; bid -= QD + KD; }
    int i = bid;
    int j = threadIdx.x;
    arow[j] = A[(size_t)i * HID + j];
    __syncthreads();
    const float* wrow = Win + (size_t)(off + j) * HID;
    float acc = 0.f;
    for (int k = 0; k < HID; ++k) acc += arow[k] * wrow[k];
    Out[(size_t)i * HID + j] = acc;
}

// WeffO[i][j] = sum_k mha_ow[i][k] * Wo[k][j]
__global__ void k_fuse_o(const float* __restrict__ Wmo,
                         const float* __restrict__ Wo,
                         float* __restrict__ WeffO) {
    __shared__ float arow[HID];
    int i = blockIdx.x, j = threadIdx.x;
    arow[j] = Wmo[(size_t)i * HID + j];
    __syncthreads();
    float acc = 0.f;
    for (int k = 0; k < HID; ++k) acc += arow[k] * Wo[(size_t)k * QD + j];
    WeffO[(size_t)i * QD + j] = acc;
}

__global__ void k_fuse_bias(const float* __restrict__ bq,
                            const float* __restrict__ bk,
                            const float* __restrict__ bv,
                            const float* __restrict__ Win,
                            const float* __restrict__ binp,
                            const float* __restrict__ mob,
                            const float* __restrict__ Wo,
                            const float* __restrict__ bo,
                            float* __restrict__ beffQ, float* __restrict__ beffK,
                            float* __restrict__ beffV, float* __restrict__ beffO) {
    int j = threadIdx.x, m = blockIdx.x;
    float acc = 0.f;
    if (m < 3) {
        const float* b = (m == 0) ? bq : (m == 1) ? bk : bv;
        int off = m * HID;
        const float* wrow = Win + (size_t)(off + j) * HID;
        for (int k = 0; k < HID; ++k) acc += b[k] * wrow[k];
        acc += binp[off + j];
        float* o = (m == 0) ? beffQ : (m == 1) ? beffK : beffV;
        o[j] = acc;
    } else {
        for (int k = 0; k < HID; ++k) acc += mob[k] * Wo[(size_t)k * QD + j];
        acc += bo[j];
        beffO[j] = acc;
    }
}

// Z[r][t] = bias[t] + sum_k X[r][k] * W[k][t]  (+ residual), 8 rows per block
template <int K>
__global__ void k_proj(const float* __restrict__ X, const float* __restrict__ W,
                       const float* __restrict__ bias,
                       const float* __restrict__ res,
                       float* __restrict__ Z) {
    __shared__ float xs[8][K];
    int r0 = blockIdx.x * 8;
    int t = threadIdx.x;
    for (int r = 0; r < 8; ++r)
        for (int k = t; k < K; k += 256)
            xs[r][k] = X[(size_t)(r0 + r) * K + k];
    __syncthreads();
    float acc[8];
    float b = bias[t];
#pragma unroll
    for (int r = 0; r < 8; ++r) acc[r] = b;
    for (int k = 0; k < K; ++k) {
        float w = W[(size_t)k * HID + t];
#pragma unroll
        for (int r = 0; r < 8; ++r) acc[r] += xs[r][k] * w;
    }
#pragma unroll
    for (int r = 0; r < 8; ++r) {
        float v = acc[r];
        if (res) v += res[(size_t)(r0 + r) * HID + t];
        Z[(size_t)(r0 + r) * HID + t] = v;
    }
}

// one block per query; 256 threads = 8 heads x 32 dims; online softmax over
// the query's (contiguous) key batch range
__global__ void k_attn(const float* __restrict__ q2, const float* __restrict__ k2,
                       const float* __restrict__ v2, const int* __restrict__ qb,
                       const int* __restrict__ kstart, const int* __restrict__ kend,
                       float* __restrict__ ctx) {
    int q = blockIdx.x;
    int t = threadIdx.x;  // t = h*32 + d
    float qv = q2[(size_t)q * HID + t] * ATT_SCALE;
    int b = qb[q];
    int j0 = kstart[b], j1 = kend[b];
    float m = -1e30f, l = 0.f, acc = 0.f;
    for (int j = j0; j < j1; ++j) {
        float kv = k2[(size_t)j * HID + t];
        float s = qv * kv;
        s += __shfl_xor(s, 16, 32);
        s += __shfl_xor(s, 8, 32);
        s += __shfl_xor(s, 4, 32);
        s += __shfl_xor(s, 2, 32);
        s += __shfl_xor(s, 1, 32);
        float vv = v2[(size_t)j * HID + t];
        if (s <= m) {
            float p = __expf(s - m);
            l += p;
            acc += p * vv;
        } else {
            float c = __expf(m - s);
            l = l * c + 1.f;
            acc = acc * c + vv;
            m = s;
        }
    }
    ctx[(size_t)q * HID + t] = (l > 0.f) ? (acc / l) : 0.f;
}

__global__ void k_ln(const float* __restrict__ X, const float* __restrict__ g,
                     const float* __restrict__ bb, void* __restrict__ out,
                     const int* __restrict__ flag) {
    __shared__ float red[8];
    int q = blockIdx.x, t = threadIdx.x;
    float x = X[(size_t)q * QD + t];
    float s = x, ss = x * x;
    for (int off = 32; off; off >>= 1) {
        s += __shfl_xor(s, off, 64);
        ss += __shfl_xor(ss, off, 64);
    }
    int w = t >> 6;
    if ((t & 63) == 0) { red[w] = s; red[4 + w] = ss; }
    __syncthreads();
    s = red[0] + red[1] + red[2] + red[3];
    ss = red[4] + red[5] + red[6] + red[7];
    float mu = s * (1.f / QD);
    float var = ss * (1.f / QD) - mu * mu;
    float inv = rsqrtf(var + LN_EPS);
    float y = (x - mu) * inv * g[t] + bb[t];
    size_t idx = (size_t)q * QD + t;
    if (*flag)
        ((__hip_bfloat16*)out)[idx] = (__hip_bfloat16)y;
    else
        ((float*)out)[idx] = y;
}

extern "C" void kernel_launch(void* const* d_in, const int* in_sizes, int n_in,
                              void* d_out, int out_size, void* d_ws, size_t ws_size,
                              hipStream_t stream) {
    const int* qbi = (const int*)d_in[16];
    const int* kbi = (const int*)d_in[17];

    float* w = (float*)d_ws;
    float* q2    = w + OFF_Q2;
    float* k2    = w + OFF_K2;
    float* v2    = w + OFF_V2;
    float* ctx   = w + OFF_CTX;
    float* WeffQ = w + OFF_WEFFQ;
    float* WeffK = w + OFF_WEFFK;
    float* WeffV = w + OFF_WEFFV;
    float* WeffO = w + OFF_WEFFO;
    float* beffQ = w + OFF_BEFFQ;
    float* beffK = w + OFF_BEFFK;
    float* beffV = w + OFF_BEFFV;
    float* beffO = w + OFF_BEFFO;
    int*   kst   = (int*)(w + OFF_KST);
    int*   ken   = (int*)(w + OFF_KEN);
    int*   flag  = (int*)(w + OFF_FLAG);
    float* xres  = k2;  // reuse: k2 dead after attention

    // f32 copies of all float inputs
    float* fin[16];
    const int foff[16] = {OFF_QNF, OFF_KNF, OFF_WQF, OFF_BQF, OFF_WKF, OFF_BKF,
                          OFF_WVF, OFF_BVF, OFF_WINF, OFF_BINPF, OFF_MOWF,
                          OFF_MOBF, OFF_WOF, OFF_BOF, OFF_LNGF, OFF_LNBF};
    for (int i = 0; i < 16; ++i) fin[i] = w + foff[i];

    k_detect<<<1, 256, 0, stream>>>((const unsigned short*)d_in[0], flag);
    for (int i = 0; i < 16; ++i) {
        int n = in_sizes[i];
        k_cvt<<<(n + 255) / 256, 256, 0, stream>>>(d_in[i], fin[i], n, flag);
    }

    k_ranges<<<1, 256, 0, stream>>>(kbi, kst, ken);
    k_fuse_qkv<<<QD + KD + KD, 256, 0, stream>>>(fin[2], fin[4], fin[6], fin[8],
                                                 WeffQ, WeffK, WeffV);
    k_fuse_o<<<HID, 256, 0, stream>>>(fin[10], fin[12], WeffO);
    k_fuse_bias<<<4, 256, 0, stream>>>(fin[3], fin[5], fin[7], fin[8], fin[9],
                                       fin[11], fin[12], fin[13],
                                       beffQ, beffK, beffV, beffO);
    k_proj<QD><<<NQ / 8, 256, 0, stream>>>(fin[0], WeffQ, beffQ, nullptr, q2);
    k_proj<KD><<<NK / 8, 256, 0, stream>>>(fin[1], WeffK, beffK, nullptr, k2);
    k_proj<KD><<<NK / 8, 256, 0, stream>>>(fin[1], WeffV, beffV, nullptr, v2);
    k_attn<<<NQ, 256, 0, stream>>>(q2, k2, v2, qbi, kst, ken, ctx);
    k_proj<HID><<<NQ / 8, 256, 0, stream>>>(ctx, WeffO, beffO, fin[0], xres);
    k_ln<<<NQ, 256, 0, stream>>>(xres, fin[14], fin[15], d_out, flag);
}

// Round 3
// 369.905 us; speedup vs baseline: 1.7506x; 1.7506x over previous
//
#include <hip/hip_runtime.h>
#include <hip/hip_bf16.h>
#include <math.h>
#include <string.h>

#define NQ 4096
#define NK 4096
#define QD 256
#define KD 320
#define HID 256
#define NH 8
#define DH 32
#define NB 16
#define LN_EPS 1e-5f
#define ATT_SCALE 0.17677669529663687f   // 1/sqrt(32)

// ---------------------------------------------------------------------------
// ws layout (float offsets) — ~29.6 MB total (same footprint as round 2)
//   OFF_Q2 region holds q2b (bf16, 2MB of the 4MB slot); same for K2/V2.
//   xres (f32, 4MB) reuses the K2 slot after attention.
// ---------------------------------------------------------------------------
#define OFF_Q2     0
#define OFF_K2     1048576
#define OFF_V2     2097152
#define OFF_CTX    3145728
#define OFF_WEFFQ  4194304
#define OFF_WEFFK  4259840
#define OFF_WEFFV  4341760
#define OFF_WEFFO  4423680
#define OFF_BEFFQ  4489216
#define OFF_BEFFK  4489472
#define OFF_BEFFV  4489728
#define OFF_BEFFO  4489984
#define OFF_KST    4490240   // 16 ints
#define OFF_KEN    4490256   // 16 ints
#define OFF_FLAG   4490272   // 1 int
#define OFF_QNF    4490304
#define OFF_KNF    5538880
#define OFF_WQF    6849600
#define OFF_BQF    6915136
#define OFF_WKF    6915392
#define OFF_BKF    6997312
#define OFF_WVF    6997568
#define OFF_BVF    7079488
#define OFF_WINF   7079744
#define OFF_BINPF  7276352
#define OFF_MOWF   7277120
#define OFF_MOBF   7342656
#define OFF_WOF    7342912
#define OFF_BOF    7408448
#define OFF_LNGF   7408704
#define OFF_LNBF   7408960
// end 7409216 floats

typedef __attribute__((ext_vector_type(8))) short bf16x8_t;
typedef __attribute__((ext_vector_type(4))) short bf16x4_t;
typedef __attribute__((ext_vector_type(4))) float f32x4_t;

__device__ __forceinline__ float bf16_bits_to_f(unsigned short s) {
    unsigned int u = (unsigned int)s << 16;
    float f;
    __builtin_memcpy(&f, &u, 4);
    return f;
}

__device__ __forceinline__ unsigned short f_to_bf16_bits(float v) {
    __hip_bfloat16 t = (__hip_bfloat16)v;
    unsigned short b;
    __builtin_memcpy(&b, &t, 2);
    return b;
}

// ---------------------------------------------------------------------------
// dtype probe: bf16 (flag=1) vs f32 (flag=0). Reads first 8KB of query_nodes.
// ---------------------------------------------------------------------------
__global__ void k_detect(const unsigned short* __restrict__ probe,
                         int* __restrict__ flag) {
    __shared__ float red[4];
    int t = threadIdx.x;
    float mx = 0.f;
    for (int i = t; i < 4096; i += 256) {
        float f = fabsf(bf16_bits_to_f(probe[i]));
        if (!(f == f)) f = 1e38f;
        mx = fmaxf(mx, f);
    }
    for (int off = 32; off; off >>= 1) mx = fmaxf(mx, __shfl_xor(mx, off, 64));
    if ((t & 63) == 0) red[t >> 6] = mx;
    __syncthreads();
    if (t == 0) {
        mx = fmaxf(fmaxf(red[0], red[1]), fmaxf(red[2], red[3]));
        *flag = (mx < 100.f) ? 1 : 0;
    }
}

// ---------------------------------------------------------------------------
// fused conversion of all 16 float tensors to f32 scratch (one launch)
// ---------------------------------------------------------------------------
struct Ptrs16 { const void* p[16]; };

#define CVT_TOTAL 2918912

__global__ void k_cvt_all(Ptrs16 ps, float* __restrict__ ws,
                          const int* __restrict__ flag) {
    const int ns[16]   = {1048576,1310720,65536,256,81920,256,81920,256,
                          196608,768,65536,256,65536,256,256,256};
    const int doff[16] = {OFF_QNF,OFF_KNF,OFF_WQF,OFF_BQF,OFF_WKF,OFF_BKF,
                          OFF_WVF,OFF_BVF,OFF_WINF,OFF_BINPF,OFF_MOWF,
                          OFF_MOBF,OFF_WOF,OFF_BOF,OFF_LNGF,OFF_LNBF};
    int gid = blockIdx.x * 256 + threadIdx.x;
    if (gid >= CVT_TOTAL) return;
    int fl = *flag;
    int base = 0;
#pragma unroll
    for (int s = 0; s < 16; ++s) {
        int n = ns[s];
        if (gid < base + n) {
            int i = gid - base;
            float v = fl ? bf16_bits_to_f(((const unsigned short*)ps.p[s])[i])
                         : ((const float*)ps.p[s])[i];
            ws[doff[s] + i] = v;
            return;
        }
        base += n;
    }
}

__global__ void k_ranges(const int* __restrict__ kb, int* __restrict__ kstart,
                         int* __restrict__ kend) {
    int t = threadIdx.x;
    if (t < NB) { kstart[t] = NK; kend[t] = 0; }
    __syncthreads();
    for (int j = t; j < NK; j += 256) {
        int b = kb[j];
        atomicMin(&kstart[b], j);
        atomicMax(&kend[b], j + 1);
    }
}

// ---------------------------------------------------------------------------
// fused weight/bias folding (one launch, 1156 blocks)
//   blocks [0,896)    : Weff{Q,K,V}[i][j] = sum_k A[i][k] * Win[off+j][k]
//   blocks [896,1152) : WeffO[i][j] = sum_k mha_ow[i][k] * Wo[k][j]
//   blocks [1152,1156): biases
// ---------------------------------------------------------------------------
__global__ void k_fuse_all(const float* __restrict__ Wq, const float* __restrict__ Wk,
                           const float* __restrict__ Wv, const float* __restrict__ Win,
                           const float* __restrict__ Wmo, const float* __restrict__ Wo,
                           const float* __restrict__ bq, const float* __restrict__ bk,
                           const float* __restrict__ bv, const float* __restrict__ binp,
                           const float* __restrict__ mob, const float* __restrict__ bo,
                           float* __restrict__ WeffQ, float* __restrict__ WeffK,
                           float* __restrict__ WeffV, float* __restrict__ WeffO,
                           float* __restrict__ beffQ, float* __restrict__ beffK,
                           float* __restrict__ beffV, float* __restrict__ beffO) {
    __shared__ float arow[HID];
    int bid = blockIdx.x;
    int j = threadIdx.x;
    if (bid < QD + KD + KD) {
        const float* A; float* Out; int off;
        if (bid < QD)           { A = Wq; Out = WeffQ; off = 0; }
        else if (bid < QD + KD) { A = Wk; Out = WeffK; off = HID;   bid -= QD; }
        else                    { A = Wv; Out = WeffV; off = 2*HID; bid -= QD + KD; }
        int i = bid;
        arow[j] = A[(size_t)i * HID + j];
        __syncthreads();
        const float4* wrow = (const float4*)(Win + (size_t)(off + j) * HID);
        float acc = 0.f;
        for (int k = 0; k < HID / 4; ++k) {
            float4 w4 = wrow[k];
            acc += arow[4*k] * w4.x + arow[4*k+1] * w4.y +
                   arow[4*k+2] * w4.z + arow[4*k+3] * w4.w;
        }
        Out[(size_t)i * HID + j] = acc;
    } else if (bid < QD + KD + KD + HID) {
        int i = bid - (QD + KD + KD);
        arow[j] = Wmo[(size_t)i * HID + j];
        __syncthreads();
        float acc = 0.f;
        for (int k = 0; k < HID; ++k) acc += arow[k] * Wo[(size_t)k * QD + j];
        WeffO[(size_t)i * QD + j] = acc;
    } else {
        int m = bid - (QD + KD + KD + HID);
        float acc = 0.f;
        if (m < 3) {
            const float* b = (m == 0) ? bq : (m == 1) ? bk : bv;
            int off = m * HID;
            const float* wrow = Win + (size_t)(off + j) * HID;
            for (int k = 0; k < HID; ++k) acc += b[k] * wrow[k];
            acc += binp[off + j];
            float* o = (m == 0) ? beffQ : (m == 1) ? beffK : beffV;
            o[j] = acc;
        } else {
            for (int k = 0; k < HID; ++k) acc += mob[k] * Wo[(size_t)k * QD + j];
            acc += bo[j];
            beffO[j] = acc;
        }
    }
}

// ---------------------------------------------------------------------------
// projection: Z[r][t] = bias[t] + sum_k X[r][k] * W[k][t] (+res), 8 rows/block
// OUTBF=1 -> write bf16 (for attention operands), else f32
// ---------------------------------------------------------------------------
template <int K, int OUTBF>
__global__ void k_proj(const float* __restrict__ X, const float* __restrict__ W,
                       const float* __restrict__ bias,
                       const float* __restrict__ res, void* __restrict__ Z) {
    __shared__ float xs[8][K];
    int r0 = blockIdx.x * 8;
    int t = threadIdx.x;
    for (int r = 0; r < 8; ++r)
        for (int k = t; k < K; k += 256)
            xs[r][k] = X[(size_t)(r0 + r) * K + k];
    __syncthreads();
    float acc[8];
    float b = bias[t];
#pragma unroll
    for (int r = 0; r < 8; ++r) acc[r] = b;
    for (int k = 0; k < K; ++k) {
        float w = W[(size_t)k * HID + t];
#pragma unroll
        for (int r = 0; r < 8; ++r) acc[r] += xs[r][k] * w;
    }
#pragma unroll
    for (int r = 0; r < 8; ++r) {
        float v = acc[r];
        if (res) v += res[(size_t)(r0 + r) * HID + t];
        size_t idx = (size_t)(r0 + r) * HID + t;
        if (OUTBF)
            ((unsigned short*)Z)[idx] = f_to_bf16_bits(v);
        else
            ((float*)Z)[idx] = v;
    }
}

// ---------------------------------------------------------------------------
// MFMA flash attention. Grid: (NQ/16)*2 blocks, 256 threads = 4 waves.
// Wave = one (16-query tile, head). S^T = K·Q^T via mfma_16x16x32_bf16 puts
// P directly in the A-operand layout of mfma_16x16x16bf16_1k for P·V.
// ---------------------------------------------------------------------------
__global__ __launch_bounds__(256) void k_attn_mfma(
        const unsigned short* __restrict__ q2b,
        const unsigned short* __restrict__ k2b,
        const unsigned short* __restrict__ v2b,
        const int* __restrict__ qb, const int* __restrict__ kst,
        const int* __restrict__ ken, float* __restrict__ ctx) {
    int wave = threadIdx.x >> 6;
    int lane = threadIdx.x & 63;
    int qt = blockIdx.x >> 1;
    int h  = ((blockIdx.x & 1) << 2) | wave;
    int q0 = qt * 16;
    int col  = lane & 15;   // S-phase: query; O-phase: dh
    int quad = lane >> 4;

    int qq = q0 + col;
    int bq_ = qb[qq];
    int j0q = kst[bq_], j1q = ken[bq_];
    int jlo = j0q, jhi = j1q;
#pragma unroll
    for (int off = 1; off < 16; off <<= 1) {
        jlo = min(jlo, __shfl_xor(jlo, off, 64));
        jhi = max(jhi, __shfl_xor(jhi, off, 64));
    }

    bf16x8_t qf = *(const bf16x8_t*)(q2b + (size_t)qq * HID + h * DH + quad * 8);

    f32x4_t accO = {0.f, 0.f, 0.f, 0.f};
    float m_st = -1e30f, l_st = 0.f;

    for (int kt = jlo; kt < jhi; kt += 16) {
        int krow = kt + col;
        if (krow > NK - 1) krow = NK - 1;
        bf16x8_t kf = *(const bf16x8_t*)(k2b + (size_t)krow * HID + h * DH + quad * 8);
        unsigned short vr[4];
#pragma unroll
        for (int j = 0; j < 4; ++j) {
            int vrow = kt + quad * 4 + j;
            if (vrow > NK - 1) vrow = NK - 1;
            vr[j] = v2b[(size_t)vrow * HID + h * DH + col];
        }
        // S^T tile: row = key (quad*4+reg), col = query (lane&15)
        f32x4_t S = __builtin_amdgcn_mfma_f32_16x16x32_bf16(
            kf, qf, (f32x4_t){0.f, 0.f, 0.f, 0.f}, 0, 0, 0);

        float s[4];
        float mt = -3e38f;
#pragma unroll
        for (int r = 0; r < 4; ++r) {
            int kk = kt + quad * 4 + r;
            bool ok = (kk >= j0q) && (kk < j1q);
            s[r] = ok ? S[r] * ATT_SCALE : -3e38f;
            mt = fmaxf(mt, s[r]);
        }
        mt = fmaxf(mt, __shfl_xor(mt, 16, 64));
        mt = fmaxf(mt, __shfl_xor(mt, 32, 64));
        float m_new = fmaxf(m_st, mt);
        float alpha = __expf(m_st - m_new);
        float p[4], ps = 0.f;
#pragma unroll
        for (int r = 0; r < 4; ++r) { p[r] = __expf(s[r] - m_new); ps += p[r]; }
        ps += __shfl_xor(ps, 16, 64);
        ps += __shfl_xor(ps, 32, 64);
        l_st = l_st * alpha + ps;
        m_st = m_new;

        bf16x4_t pb, vb;
#pragma unroll
        for (int r = 0; r < 4; ++r) {
            pb[r] = (short)f_to_bf16_bits(p[r]);
            vb[r] = (short)vr[r];
        }
        // rescale O accumulator rows (query = quad*4+r) by that query's alpha
#pragma unroll
        for (int r = 0; r < 4; ++r) {
            float aq = __shfl(alpha, quad * 4 + r, 64);
            accO[r] *= aq;
        }
        accO = __builtin_amdgcn_mfma_f32_16x16x16bf16_1k(pb, vb, accO, 0, 0, 0);
    }

#pragma unroll
    for (int r = 0; r < 4; ++r) {
        float lq = __shfl(l_st, quad * 4 + r, 64);
        float o = (lq > 0.f) ? accO[r] / lq : 0.f;
        int qrow = q0 + quad * 4 + r;
        ctx[(size_t)qrow * HID + h * DH + col] = o;
    }
}

__global__ void k_ln(const float* __restrict__ X, const float* __restrict__ g,
                     const float* __restrict__ bb, void* __restrict__ out,
                     const int* __restrict__ flag) {
    __shared__ float red[8];
    int q = blockIdx.x, t = threadIdx.x;
    float x = X[(size_t)q * QD + t];
    float s = x, ss = x * x;
    for (int off = 32; off; off >>= 1) {
        s += __shfl_xor(s, off, 64);
        ss += __shfl_xor(ss, off, 64);
    }
    int w = t >> 6;
    if ((t & 63) == 0) { red[w] = s; red[4 + w] = ss; }
    __syncthreads();
    s = red[0] + red[1] + red[2] + red[3];
    ss = red[4] + red[5] + red[6] + red[7];
    float mu = s * (1.f / QD);
    float var = ss * (1.f / QD) - mu * mu;
    float inv = rsqrtf(var + LN_EPS);
    float y = (x - mu) * inv * g[t] + bb[t];
    size_t idx = (size_t)q * QD + t;
    if (*flag)
        ((__hip_bfloat16*)out)[idx] = (__hip_bfloat16)y;
    else
        ((float*)out)[idx] = y;
}

extern "C" void kernel_launch(void* const* d_in, const int* in_sizes, int n_in,
                              void* d_out, int out_size, void* d_ws, size_t ws_size,
                              hipStream_t stream) {
    const int* qbi = (const int*)d_in[16];
    const int* kbi = (const int*)d_in[17];

    float* w = (float*)d_ws;
    unsigned short* q2b = (unsigned short*)(w + OFF_Q2);
    unsigned short* k2b = (unsigned short*)(w + OFF_K2);
    unsigned short* v2b = (unsigned short*)(w + OFF_V2);
    float* ctx   = w + OFF_CTX;
    float* WeffQ = w + OFF_WEFFQ;
    float* WeffK = w + OFF_WEFFK;
    float* WeffV = w + OFF_WEFFV;
    float* WeffO = w + OFF_WEFFO;
    float* beffQ = w + OFF_BEFFQ;
    float* beffK = w + OFF_BEFFK;
    float* beffV = w + OFF_BEFFV;
    float* beffO = w + OFF_BEFFO;
    int*   kst   = (int*)(w + OFF_KST);
    int*   ken   = (int*)(w + OFF_KEN);
    int*   flag  = (int*)(w + OFF_FLAG);
    float* xres  = w + OFF_K2;   // f32, reuses K2 slot (k2b dead after attn)

    float* fin[16];
    const int foff[16] = {OFF_QNF, OFF_KNF, OFF_WQF, OFF_BQF, OFF_WKF, OFF_BKF,
                          OFF_WVF, OFF_BVF, OFF_WINF, OFF_BINPF, OFF_MOWF,
                          OFF_MOBF, OFF_WOF, OFF_BOF, OFF_LNGF, OFF_LNBF};
    for (int i = 0; i < 16; ++i) fin[i] = w + foff[i];

    Ptrs16 ps;
    for (int i = 0; i < 16; ++i) ps.p[i] = d_in[i];

    k_detect<<<1, 256, 0, stream>>>((const unsigned short*)d_in[0], flag);
    k_cvt_all<<<(CVT_TOTAL + 255) / 256, 256, 0, stream>>>(ps, w, flag);
    k_ranges<<<1, 256, 0, stream>>>(kbi, kst, ken);
    k_fuse_all<<<QD + KD + KD + HID + 4, 256, 0, stream>>>(
        fin[2], fin[4], fin[6], fin[8], fin[10], fin[12],
        fin[3], fin[5], fin[7], fin[9], fin[11], fin[13],
        WeffQ, WeffK, WeffV, WeffO, beffQ, beffK, beffV, beffO);
    k_proj<QD, 1><<<NQ / 8, 256, 0, stream>>>(fin[0], WeffQ, beffQ, nullptr, q2b);
    k_proj<KD, 1><<<NK / 8, 256, 0, stream>>>(fin[1], WeffK, beffK, nullptr, k2b);
    k_proj<KD, 1><<<NK / 8, 256, 0, stream>>>(fin[1], WeffV, beffV, nullptr, v2b);
    k_attn_mfma<<<(NQ / 16) * 2, 256, 0, stream>>>(q2b, k2b, v2b, qbi, kst, ken, ctx);
    k_proj<HID, 0><<<NQ / 8, 256, 0, stream>>>(ctx, WeffO, beffO, fin[0], xres);
    k_ln<<<NQ, 256, 0, stream>>>(xres, fin[14], fin[15], d_out, flag);
}

// Round 4
// 299.674 us; speedup vs baseline: 2.1609x; 1.2344x over previous
//
#include <hip/hip_runtime.h>
#include <hip/hip_bf16.h>
#include <math.h>
#include <string.h>

#define NQ 4096
#define NK 4096
#define QD 256
#define KD 320
#define HID 256
#define NH 8
#define DH 32
#define NB 16
#define LN_EPS 1e-5f
#define ATT_SCALE 0.17677669529663687f   // 1/sqrt(32)

// ---------------------------------------------------------------------------
// ws layout (float offsets) — ~29.6 MB total
// ---------------------------------------------------------------------------
#define OFF_Q2     0
#define OFF_K2     1048576
#define OFF_V2     2097152
#define OFF_CTX    3145728
#define OFF_WEFFQ  4194304
#define OFF_WEFFK  4259840
#define OFF_WEFFV  4341760
#define OFF_WEFFO  4423680
#define OFF_BEFFQ  4489216
#define OFF_BEFFK  4489472
#define OFF_BEFFV  4489728
#define OFF_BEFFO  4489984
#define OFF_KST    4490240   // 16 ints
#define OFF_KEN    4490256   // 16 ints
#define OFF_FLAG   4490272   // 1 int
#define OFF_QNF    4490304
#define OFF_KNF    5538880
#define OFF_WQF    6849600
#define OFF_BQF    6915136
#define OFF_WKF    6915392
#define OFF_BKF    6997312
#define OFF_WVF    6997568
#define OFF_BVF    7079488
#define OFF_WINF   7079744
#define OFF_BINPF  7276352
#define OFF_MOWF   7277120
#define OFF_MOBF   7342656
#define OFF_WOF    7342912
#define OFF_BOF    7408448
#define OFF_LNGF   7408704
#define OFF_LNBF   7408960
// end 7409216 floats

typedef __attribute__((ext_vector_type(8))) short bf16x8_t;
typedef __attribute__((ext_vector_type(4))) short bf16x4_t;
typedef __attribute__((ext_vector_type(4))) float f32x4_t;

__device__ __forceinline__ float bf16_bits_to_f(unsigned short s) {
    unsigned int u = (unsigned int)s << 16;
    float f;
    __builtin_memcpy(&f, &u, 4);
    return f;
}

__device__ __forceinline__ unsigned short f_to_bf16_bits(float v) {
    __hip_bfloat16 t = (__hip_bfloat16)v;
    unsigned short b;
    __builtin_memcpy(&b, &t, 2);
    return b;
}

// ---------------------------------------------------------------------------
// dtype probe: bf16 (flag=1) vs f32 (flag=0). Reads first 8KB of query_nodes.
// ---------------------------------------------------------------------------
__global__ void k_detect(const unsigned short* __restrict__ probe,
                         int* __restrict__ flag) {
    __shared__ float red[4];
    int t = threadIdx.x;
    float mx = 0.f;
    for (int i = t; i < 4096; i += 256) {
        float f = fabsf(bf16_bits_to_f(probe[i]));
        if (!(f == f)) f = 1e38f;
        mx = fmaxf(mx, f);
    }
    for (int off = 32; off; off >>= 1) mx = fmaxf(mx, __shfl_xor(mx, off, 64));
    if ((t & 63) == 0) red[t >> 6] = mx;
    __syncthreads();
    if (t == 0) {
        mx = fmaxf(fmaxf(red[0], red[1]), fmaxf(red[2], red[3]));
        *flag = (mx < 100.f) ? 1 : 0;
    }
}

// ---------------------------------------------------------------------------
// fused conversion of all 16 float tensors to f32 scratch (one launch)
// ---------------------------------------------------------------------------
struct Ptrs16 { const void* p[16]; };

#define CVT_TOTAL 2918912

__global__ void k_cvt_all(Ptrs16 ps, float* __restrict__ ws,
                          const int* __restrict__ flag) {
    const int ns[16]   = {1048576,1310720,65536,256,81920,256,81920,256,
                          196608,768,65536,256,65536,256,256,256};
    const int doff[16] = {OFF_QNF,OFF_KNF,OFF_WQF,OFF_BQF,OFF_WKF,OFF_BKF,
                          OFF_WVF,OFF_BVF,OFF_WINF,OFF_BINPF,OFF_MOWF,
                          OFF_MOBF,OFF_WOF,OFF_BOF,OFF_LNGF,OFF_LNBF};
    int gid = blockIdx.x * 256 + threadIdx.x;
    if (gid >= CVT_TOTAL) return;
    int fl = *flag;
    int base = 0;
#pragma unroll
    for (int s = 0; s < 16; ++s) {
        int n = ns[s];
        if (gid < base + n) {
            int i = gid - base;
            float v = fl ? bf16_bits_to_f(((const unsigned short*)ps.p[s])[i])
                         : ((const float*)ps.p[s])[i];
            ws[doff[s] + i] = v;
            return;
        }
        base += n;
    }
}

// ---------------------------------------------------------------------------
// batch ranges from SORTED key_batch_idx: boundary detection, no atomics.
// Each batch slot is written by exactly one thread (the boundary crosser),
// empty batches get [j,j) filled by the same thread.
// ---------------------------------------------------------------------------
__global__ void k_ranges(const int* __restrict__ kb, int* __restrict__ kstart,
                         int* __restrict__ kend) {
    int j = blockIdx.x * 256 + threadIdx.x;
    if (j >= NK) return;
    int b = kb[j];
    if (j == 0) {
        for (int x = 0; x < b; ++x) { kstart[x] = 0; kend[x] = 0; }
        kstart[b] = 0;
    } else {
        int bp = kb[j - 1];
        if (bp != b) {
            kend[bp] = j;
            for (int x = bp + 1; x < b; ++x) { kstart[x] = j; kend[x] = j; }
            kstart[b] = j;
        }
    }
    if (j == NK - 1) {
        kend[b] = NK;
        for (int x = b + 1; x < NB; ++x) { kstart[x] = NK; kend[x] = NK; }
    }
}

// ---------------------------------------------------------------------------
// fused weight/bias folding (one launch, 1156 blocks)
// ---------------------------------------------------------------------------
__global__ void k_fuse_all(const float* __restrict__ Wq, const float* __restrict__ Wk,
                           const float* __restrict__ Wv, const float* __restrict__ Win,
                           const float* __restrict__ Wmo, const float* __restrict__ Wo,
                           const float* __restrict__ bq, const float* __restrict__ bk,
                           const float* __restrict__ bv, const float* __restrict__ binp,
                           const float* __restrict__ mob, const float* __restrict__ bo,
                           float* __restrict__ WeffQ, float* __restrict__ WeffK,
                           float* __restrict__ WeffV, float* __restrict__ WeffO,
                           float* __restrict__ beffQ, float* __restrict__ beffK,
                           float* __restrict__ beffV, float* __restrict__ beffO) {
    __shared__ float arow[HID];
    int bid = blockIdx.x;
    int j = threadIdx.x;
    if (bid < QD + KD + KD) {
        const float* A; float* Out; int off;
        if (bid < QD)           { A = Wq; Out = WeffQ; off = 0; }
        else if (bid < QD + KD) { A = Wk; Out = WeffK; off = HID;   bid -= QD; }
        else                    { A = Wv; Out = WeffV; off = 2*HID; bid -= QD + KD; }
        int i = bid;
        arow[j] = A[(size_t)i * HID + j];
        __syncthreads();
        const float4* wrow = (const float4*)(Win + (size_t)(off + j) * HID);
        float acc = 0.f;
        for (int k = 0; k < HID / 4; ++k) {
            float4 w4 = wrow[k];
            acc += arow[4*k] * w4.x + arow[4*k+1] * w4.y +
                   arow[4*k+2] * w4.z + arow[4*k+3] * w4.w;
        }
        Out[(size_t)i * HID + j] = acc;
    } else if (bid < QD + KD + KD + HID) {
        int i = bid - (QD + KD + KD);
        arow[j] = Wmo[(size_t)i * HID + j];
        __syncthreads();
        float acc = 0.f;
        for (int k = 0; k < HID; ++k) acc += arow[k] * Wo[(size_t)k * QD + j];
        WeffO[(size_t)i * QD + j] = acc;
    } else {
        int m = bid - (QD + KD + KD + HID);
        float acc = 0.f;
        if (m < 3) {
            const float* b = (m == 0) ? bq : (m == 1) ? bk : bv;
            int off = m * HID;
            const float* wrow = Win + (size_t)(off + j) * HID;
            for (int k = 0; k < HID; ++k) acc += b[k] * wrow[k];
            acc += binp[off + j];
            float* o = (m == 0) ? beffQ : (m == 1) ? beffK : beffV;
            o[j] = acc;
        } else {
            for (int k = 0; k < HID; ++k) acc += mob[k] * Wo[(size_t)k * QD + j];
            acc += bo[j];
            beffO[j] = acc;
        }
    }
}

// ---------------------------------------------------------------------------
// projection: Z[r][t] = bias[t] + sum_k X[r][k] * W[k][t] (+res)
// 16 rows/block; X read via wave-uniform addresses -> scalar (s_load) path,
// W via coalesced vector loads. No LDS.
// ---------------------------------------------------------------------------
template <int K, int OUTBF>
__global__ __launch_bounds__(256) void k_proj(const float* __restrict__ X,
                       const float* __restrict__ W,
                       const float* __restrict__ bias,
                       const float* __restrict__ res, void* __restrict__ Z) {
    int t = threadIdx.x;
    int r0 = blockIdx.x * 16;
    float b = bias[t];
    float acc[16];
#pragma unroll
    for (int r = 0; r < 16; ++r) acc[r] = b;
    const float* xbase = X + (size_t)r0 * K;
    for (int k = 0; k < K; k += 4) {
        float w0 = W[(size_t)k * HID + t];
        float w1 = W[(size_t)(k + 1) * HID + t];
        float w2 = W[(size_t)(k + 2) * HID + t];
        float w3 = W[(size_t)(k + 3) * HID + t];
#pragma unroll
        for (int r = 0; r < 16; ++r) {
            const float* xr = xbase + (size_t)r * K + k;
            acc[r] += xr[0] * w0 + xr[1] * w1 + xr[2] * w2 + xr[3] * w3;
        }
    }
#pragma unroll
    for (int r = 0; r < 16; ++r) {
        float v = acc[r];
        if (res) v += res[(size_t)(r0 + r) * HID + t];
        size_t idx = (size_t)(r0 + r) * HID + t;
        if (OUTBF)
            ((unsigned short*)Z)[idx] = f_to_bf16_bits(v);
        else
            ((float*)Z)[idx] = v;
    }
}

// ---------------------------------------------------------------------------
// MFMA flash attention. Grid: (NQ/16)*2 blocks, 256 threads = 4 waves.
// Wave = one (16-query tile, head). S^T = K·Q^T via mfma_16x16x32_bf16 puts
// P directly in the A-operand layout of mfma_16x16x16bf16_1k for P·V.
// ---------------------------------------------------------------------------
__global__ __launch_bounds__(256) void k_attn_mfma(
        const unsigned short* __restrict__ q2b,
        const unsigned short* __restrict__ k2b,
        const unsigned short* __restrict__ v2b,
        const int* __restrict__ qb, const int* __restrict__ kst,
        const int* __restrict__ ken, float* __restrict__ ctx) {
    int wave = threadIdx.x >> 6;
    int lane = threadIdx.x & 63;
    int qt = blockIdx.x >> 1;
    int h  = ((blockIdx.x & 1) << 2) | wave;
    int q0 = qt * 16;
    int col  = lane & 15;   // S-phase: query; O-phase: dh
    int quad = lane >> 4;

    int qq = q0 + col;
    int bq_ = qb[qq];
    int j0q = kst[bq_], j1q = ken[bq_];
    int jlo = j0q, jhi = j1q;
#pragma unroll
    for (int off = 1; off < 16; off <<= 1) {
        jlo = min(jlo, __shfl_xor(jlo, off, 64));
        jhi = max(jhi, __shfl_xor(jhi, off, 64));
    }

    bf16x8_t qf = *(const bf16x8_t*)(q2b + (size_t)qq * HID + h * DH + quad * 8);

    f32x4_t accO = {0.f, 0.f, 0.f, 0.f};
    float m_st = -1e30f, l_st = 0.f;

    for (int kt = jlo; kt < jhi; kt += 16) {
        int krow = kt + col;
        if (krow > NK - 1) krow = NK - 1;
        bf16x8_t kf = *(const bf16x8_t*)(k2b + (size_t)krow * HID + h * DH + quad * 8);
        unsigned short vr[4];
#pragma unroll
        for (int j = 0; j < 4; ++j) {
            int vrow = kt + quad * 4 + j;
            if (vrow > NK - 1) vrow = NK - 1;
            vr[j] = v2b[(size_t)vrow * HID + h * DH + col];
        }
        // S^T tile: row = key (quad*4+reg), col = query (lane&15)
        f32x4_t S = __builtin_amdgcn_mfma_f32_16x16x32_bf16(
            kf, qf, (f32x4_t){0.f, 0.f, 0.f, 0.f}, 0, 0, 0);

        float s[4];
        float mt = -3e38f;
#pragma unroll
        for (int r = 0; r < 4; ++r) {
            int kk = kt + quad * 4 + r;
            bool ok = (kk >= j0q) && (kk < j1q);
            s[r] = ok ? S[r] * ATT_SCALE : -3e38f;
            mt = fmaxf(mt, s[r]);
        }
        mt = fmaxf(mt, __shfl_xor(mt, 16, 64));
        mt = fmaxf(mt, __shfl_xor(mt, 32, 64));
        float m_new = fmaxf(m_st, mt);
        float alpha = __expf(m_st - m_new);
        float p[4], ps = 0.f;
#pragma unroll
        for (int r = 0; r < 4; ++r) { p[r] = __expf(s[r] - m_new); ps += p[r]; }
        ps += __shfl_xor(ps, 16, 64);
        ps += __shfl_xor(ps, 32, 64);
        l_st = l_st * alpha + ps;
        m_st = m_new;

        bf16x4_t pb, vb;
#pragma unroll
        for (int r = 0; r < 4; ++r) {
            pb[r] = (short)f_to_bf16_bits(p[r]);
            vb[r] = (short)vr[r];
        }
#pragma unroll
        for (int r = 0; r < 4; ++r) {
            float aq = __shfl(alpha, quad * 4 + r, 64);
            accO[r] *= aq;
        }
        accO = __builtin_amdgcn_mfma_f32_16x16x16bf16_1k(pb, vb, accO, 0, 0, 0);
    }

#pragma unroll
    for (int r = 0; r < 4; ++r) {
        float lq = __shfl(l_st, quad * 4 + r, 64);
        float o = (lq > 0.f) ? accO[r] / lq : 0.f;
        int qrow = q0 + quad * 4 + r;
        ctx[(size_t)qrow * HID + h * DH + col] = o;
    }
}

__global__ void k_ln(const float* __restrict__ X, const float* __restrict__ g,
                     const float* __restrict__ bb, void* __restrict__ out,
                     const int* __restrict__ flag) {
    __shared__ float red[8];
    int q = blockIdx.x, t = threadIdx.x;
    float x = X[(size_t)q * QD + t];
    float s = x, ss = x * x;
    for (int off = 32; off; off >>= 1) {
        s += __shfl_xor(s, off, 64);
        ss += __shfl_xor(ss, off, 64);
    }
    int w = t >> 6;
    if ((t & 63) == 0) { red[w] = s; red[4 + w] = ss; }
    __syncthreads();
    s = red[0] + red[1] + red[2] + red[3];
    ss = red[4] + red[5] + red[6] + red[7];
    float mu = s * (1.f / QD);
    float var = ss * (1.f / QD) - mu * mu;
    float inv = rsqrtf(var + LN_EPS);
    float y = (x - mu) * inv * g[t] + bb[t];
    size_t idx = (size_t)q * QD + t;
    if (*flag)
        ((__hip_bfloat16*)out)[idx] = (__hip_bfloat16)y;
    else
        ((float*)out)[idx] = y;
}

extern "C" void kernel_launch(void* const* d_in, const int* in_sizes, int n_in,
                              void* d_out, int out_size, void* d_ws, size_t ws_size,
                              hipStream_t stream) {
    const int* qbi = (const int*)d_in[16];
    const int* kbi = (const int*)d_in[17];

    float* w = (float*)d_ws;
    unsigned short* q2b = (unsigned short*)(w + OFF_Q2);
    unsigned short* k2b = (unsigned short*)(w + OFF_K2);
    unsigned short* v2b = (unsigned short*)(w + OFF_V2);
    float* ctx   = w + OFF_CTX;
    float* WeffQ = w + OFF_WEFFQ;
    float* WeffK = w + OFF_WEFFK;
    float* WeffV = w + OFF_WEFFV;
    float* WeffO = w + OFF_WEFFO;
    float* beffQ = w + OFF_BEFFQ;
    float* beffK = w + OFF_BEFFK;
    float* beffV = w + OFF_BEFFV;
    float* beffO = w + OFF_BEFFO;
    int*   kst   = (int*)(w + OFF_KST);
    int*   ken   = (int*)(w + OFF_KEN);
    int*   flag  = (int*)(w + OFF_FLAG);
    float* xres  = w + OFF_K2;   // f32, reuses K2 slot (k2b dead after attn)

    float* fin[16];
    const int foff[16] = {OFF_QNF, OFF_KNF, OFF_WQF, OFF_BQF, OFF_WKF, OFF_BKF,
                          OFF_WVF, OFF_BVF, OFF_WINF, OFF_BINPF, OFF_MOWF,
                          OFF_MOBF, OFF_WOF, OFF_BOF, OFF_LNGF, OFF_LNBF};
    for (int i = 0; i < 16; ++i) fin[i] = w + foff[i];

    Ptrs16 ps;
    for (int i = 0; i < 16; ++i) ps.p[i] = d_in[i];

    k_detect<<<1, 256, 0, stream>>>((const unsigned short*)d_in[0], flag);
    k_cvt_all<<<(CVT_TOTAL + 255) / 256, 256, 0, stream>>>(ps, w, flag);
    k_ranges<<<NK / 256, 256, 0, stream>>>(kbi, kst, ken);
    k_fuse_all<<<QD + KD + KD + HID + 4, 256, 0, stream>>>(
        fin[2], fin[4], fin[6], fin[8], fin[10], fin[12],
        fin[3], fin[5], fin[7], fin[9], fin[11], fin[13],
        WeffQ, WeffK, WeffV, WeffO, beffQ, beffK, beffV, beffO);
    k_proj<QD, 1><<<NQ / 16, 256, 0, stream>>>(fin[0], WeffQ, beffQ, nullptr, q2b);
    k_proj<KD, 1><<<NK / 16, 256, 0, stream>>>(fin[1], WeffK, beffK, nullptr, k2b);
    k_proj<KD, 1><<<NK / 16, 256, 0, stream>>>(fin[1], WeffV, beffV, nullptr, v2b);
    k_attn_mfma<<<(NQ / 16) * 2, 256, 0, stream>>>(q2b, k2b, v2b, qbi, kst, ken, ctx);
    k_proj<HID, 0><<<NQ / 16, 256, 0, stream>>>(ctx, WeffO, beffO, fin[0], xres);
    k_ln<<<NQ, 256, 0, stream>>>(xres, fin[14], fin[15], d_out, flag);
}

// Round 5
// 170.520 us; speedup vs baseline: 3.7976x; 1.7574x over previous
//
#include <hip/hip_runtime.h>
#include <hip/hip_bf16.h>
#include <math.h>

#define NQ 4096
#define NK 4096
#define QD 256
#define KD 320
#define HID 256
#define NH 8
#define DH 32
#define NB 16
#define LN_EPS 1e-5f
#define ATT_SCALE 0.17677669529663687f   // 1/sqrt(32)

typedef unsigned short ushort_t;
typedef __attribute__((ext_vector_type(8))) short bf16x8_t;
typedef __attribute__((ext_vector_type(4))) short bf16x4_t;
typedef __attribute__((ext_vector_type(4))) float f32x4_t;

// ---------------------------------------------------------------------------
// ws layout (float offsets), ~19 MB
// ---------------------------------------------------------------------------
#define OFF_QNB   0         // bf16 [4096][256]
#define OFF_KNB   524288    // bf16 [4096][320]
#define OFF_Q2B   1179648   // bf16 [4096][256]
#define OFF_K2B   1703936
#define OFF_V2B   2228224
#define OFF_CTXB  2752512   // bf16 [4096][256]
#define OFF_XRES  3276800   // f32  [4096][256]
#define OFF_WQB   4325376   // bf16 [256][256]   Wq rows
#define OFF_WKB   4358144   // bf16 [320][256]   Wk rows
#define OFF_WVB   4399104   // bf16 [320][256]
#define OFF_WINB  4440064   // bf16 [768][256]   in_proj_w rows
#define OFF_MOWB  4538368   // bf16 [256][256]   mha_ow rows
#define OFF_WOTB  4571136   // bf16 [256][256]   Wo TRANSPOSED: WoT[n][k]
#define OFF_WQT   4603904   // bf16 WeffQT [256][256]
#define OFF_WKT   4636672   // bf16 WeffKT [256][320]
#define OFF_WVT   4677632   // bf16 WeffVT [256][320]
#define OFF_WOT   4718592   // bf16 WeffOT [256][256]
#define OFF_BQ    4751360
#define OFF_BK    4751616
#define OFF_BV    4751872
#define OFF_BINP  4752128   // 768
#define OFF_MOB   4752896
#define OFF_BO    4753152
#define OFF_LNG   4753408
#define OFF_LNB   4753664
#define OFF_BEFFQ 4753920
#define OFF_BEFFK 4754176
#define OFF_BEFFV 4754432
#define OFF_BEFFO 4754688
#define OFF_KST   4754944   // 16 int
#define OFF_KEN   4754960   // 16 int
#define OFF_FLAG  4754976   // 1 int

__device__ __forceinline__ float bf16_bits_to_f(ushort_t s) {
    unsigned int u = (unsigned int)s << 16;
    float f;
    __builtin_memcpy(&f, &u, 4);
    return f;
}

__device__ __forceinline__ ushort_t f_to_bf16_bits(float v) {
    __hip_bfloat16 t = (__hip_bfloat16)v;
    ushort_t b;
    __builtin_memcpy(&b, &t, 2);
    return b;
}

// ---------------------------------------------------------------------------
// dtype probe: bf16 (flag=1) vs f32 (flag=0). Reads first 8KB of query_nodes.
// ---------------------------------------------------------------------------
__global__ void k_detect(const ushort_t* __restrict__ probe,
                         int* __restrict__ flag) {
    __shared__ float red[4];
    int t = threadIdx.x;
    float mx = 0.f;
    for (int i = t; i < 4096; i += 256) {
        float f = fabsf(bf16_bits_to_f(probe[i]));
        if (!(f == f)) f = 1e38f;
        mx = fmaxf(mx, f);
    }
    for (int off = 32; off; off >>= 1) mx = fmaxf(mx, __shfl_xor(mx, off, 64));
    if ((t & 63) == 0) red[t >> 6] = mx;
    __syncthreads();
    if (t == 0) {
        mx = fmaxf(fmaxf(red[0], red[1]), fmaxf(red[2], red[3]));
        *flag = (mx < 100.f) ? 1 : 0;
    }
}

// ---------------------------------------------------------------------------
// fused conversion: bf16 copies for GEMM operands (type 0), f32 for
// biases/LN (type 1), Wo transposed bf16 (type 2).
// ---------------------------------------------------------------------------
struct Ptrs16 { const void* p[16]; };

#define CVT_TOTAL 2918912

__global__ void k_cvt_all(Ptrs16 ps, float* __restrict__ ws,
                          const int* __restrict__ flag) {
    const int ns[16]   = {1048576,1310720,65536,256,81920,256,81920,256,
                          196608,768,65536,256,65536,256,256,256};
    const int doff[16] = {OFF_QNB,OFF_KNB,OFF_WQB,OFF_BQ,OFF_WKB,OFF_BK,
                          OFF_WVB,OFF_BV,OFF_WINB,OFF_BINP,OFF_MOWB,
                          OFF_MOB,OFF_WOTB,OFF_BO,OFF_LNG,OFF_LNB};
    const int typ[16]  = {0,0,0,1,0,1,0,1,0,1,0,1,2,1,1,1};
    int gid = blockIdx.x * 256 + threadIdx.x;
    if (gid >= CVT_TOTAL) return;
    int fl = *flag;
    int base = 0;
#pragma unroll
    for (int s = 0; s < 16; ++s) {
        int n = ns[s];
        if (gid < base + n) {
            int i = gid - base;
            if (typ[s] == 1) {
                float v = fl ? bf16_bits_to_f(((const ushort_t*)ps.p[s])[i])
                             : ((const float*)ps.p[s])[i];
                ws[doff[s] + i] = v;
            } else {
                ushort_t h = fl ? ((const ushort_t*)ps.p[s])[i]
                                : f_to_bf16_bits(((const float*)ps.p[s])[i]);
                ushort_t* d = (ushort_t*)(ws + doff[s]);
                int di = (typ[s] == 2) ? ((i & 255) * 256 + (i >> 8)) : i;
                d[di] = h;
            }
            return;
        }
        base += n;
    }
}

// ---------------------------------------------------------------------------
// batch ranges from SORTED key_batch_idx: boundary detection, no atomics.
// ---------------------------------------------------------------------------
__global__ void k_ranges(const int* __restrict__ kb, int* __restrict__ kstart,
                         int* __restrict__ kend) {
    int j = blockIdx.x * 256 + threadIdx.x;
    if (j >= NK) return;
    int b = kb[j];
    if (j == 0) {
        for (int x = 0; x < b; ++x) { kstart[x] = 0; kend[x] = 0; }
        kstart[b] = 0;
    } else {
        int bp = kb[j - 1];
        if (bp != b) {
            kend[bp] = j;
            for (int x = bp + 1; x < b; ++x) { kstart[x] = j; kend[x] = j; }
            kstart[b] = j;
        }
    }
    if (j == NK - 1) {
        kend[b] = NK;
        for (int x = b + 1; x < NB; ++x) { kstart[x] = NK; kend[x] = NK; }
    }
}

// ---------------------------------------------------------------------------
// shared MFMA 64x64 tile: D[m][n] = sum_k A[m][k]*B[n][k]  (A·B^T form)
// A rows: X + m*K (contiguous k), B rows: WT + n*K. No LDS, no barriers.
// Output fragment: row (A-dim) = quad*4+r, col (B-dim) = lane&15.
// ---------------------------------------------------------------------------
template <int K>
__device__ __forceinline__ void mm64(const ushort_t* __restrict__ Xrow,
                                     const ushort_t* __restrict__ Wrow,
                                     f32x4_t acc[4]) {
#pragma unroll
    for (int kc = 0; kc < K; kc += 32) {
        bf16x8_t af = *(const bf16x8_t*)(Xrow + kc);
#pragma unroll
        for (int t = 0; t < 4; ++t) {
            bf16x8_t bfrag = *(const bf16x8_t*)(Wrow + t * 16 * K + kc);
            acc[t] = __builtin_amdgcn_mfma_f32_16x16x32_bf16(af, bfrag, acc[t],
                                                             0, 0, 0);
        }
    }
}

// ---------------------------------------------------------------------------
// weight fusion: 4 small GEMMs in one launch (72 blocks).
//   WeffQT[j][i] = sum_h WinQ[j][h]·Wq[i][h]        (16 blocks)
//   WeffKT[j][c] = sum_h WinK[j][h]·Wk[c][h]        (20)
//   WeffVT[j][c] = sum_h WinV[j][h]·Wv[c][h]        (20)
//   WeffOT[n][h] = sum_k WoT[n][k]·mow[h][k]        (16)
// ---------------------------------------------------------------------------
__global__ __launch_bounds__(256) void k_fuse_gemm(
        const ushort_t* __restrict__ winb, const ushort_t* __restrict__ wqb,
        const ushort_t* __restrict__ wkb, const ushort_t* __restrict__ wvb,
        const ushort_t* __restrict__ wotb, const ushort_t* __restrict__ mowb,
        ushort_t* __restrict__ wqt, ushort_t* __restrict__ wkt,
        ushort_t* __restrict__ wvt, ushort_t* __restrict__ wot) {
    int r = blockIdx.x;
    const ushort_t *A, *B;
    ushort_t* Out;
    int N, mb, nb;
    if (r < 16)      { A = winb;          B = wqb;  Out = wqt; N = 256; mb = r >> 2;  nb = r & 3; }
    else if (r < 36) { int rr = r - 16; A = winb + 65536;  B = wkb;  Out = wkt; N = 320; mb = rr / 5; nb = rr % 5; }
    else if (r < 56) { int rr = r - 36; A = winb + 131072; B = wvb;  Out = wvt; N = 320; mb = rr / 5; nb = rr % 5; }
    else             { int rr = r - 56; A = wotb;          B = mowb; Out = wot; N = 256; mb = rr >> 2; nb = rr & 3; }
    int w = threadIdx.x >> 6, lane = threadIdx.x & 63;
    int col = lane & 15, quad = lane >> 4;
    int m0 = mb * 64 + w * 16, n0 = nb * 64;
    f32x4_t acc[4];
#pragma unroll
    for (int t = 0; t < 4; ++t) acc[t] = (f32x4_t){0.f, 0.f, 0.f, 0.f};
    mm64<256>(A + (size_t)(m0 + col) * 256 + quad * 8,
              B + (size_t)(n0 + col) * 256 + quad * 8, acc);
#pragma unroll
    for (int t = 0; t < 4; ++t)
#pragma unroll
        for (int rr = 0; rr < 4; ++rr) {
            int m = m0 + quad * 4 + rr;
            int n = n0 + t * 16 + col;
            Out[(size_t)m * N + n] = f_to_bf16_bits(acc[t][rr]);
        }
}

// ---------------------------------------------------------------------------
// effective biases (4 blocks)
// ---------------------------------------------------------------------------
__global__ void k_bias(const float* __restrict__ bq, const float* __restrict__ bk,
                       const float* __restrict__ bv, const float* __restrict__ binp,
                       const float* __restrict__ mob, const float* __restrict__ bo,
                       const ushort_t* __restrict__ winb,
                       const ushort_t* __restrict__ wotb,
                       float* __restrict__ beffQ, float* __restrict__ beffK,
                       float* __restrict__ beffV, float* __restrict__ beffO) {
    int m = blockIdx.x, j = threadIdx.x;
    float acc = 0.f;
    if (m < 3) {
        const float* b = (m == 0) ? bq : (m == 1) ? bk : bv;
        const ushort_t* wrow = winb + (size_t)(m * 256 + j) * 256;
        for (int k = 0; k < 256; ++k) acc += b[k] * bf16_bits_to_f(wrow[k]);
        acc += binp[m * 256 + j];
        float* o = (m == 0) ? beffQ : (m == 1) ? beffK : beffV;
        o[j] = acc;
    } else {
        const ushort_t* wrow = wotb + (size_t)j * 256;
        for (int k = 0; k < 256; ++k) acc += mob[k] * bf16_bits_to_f(wrow[k]);
        acc += bo[j];
        beffO[j] = acc;
    }
}

// ---------------------------------------------------------------------------
// main projection GEMM: Z[m][n] = sum_k X[m][k]·WT[n][k] + bias[n] (+res)
// grid (M/64, 4, z); z selects {WT,bias,Z} pair (for fused K/V launch).
// ---------------------------------------------------------------------------
template <int K, int OUTBF, int RES>
__global__ __launch_bounds__(256) void k_gemm(
        const ushort_t* __restrict__ X,
        const ushort_t* __restrict__ WT0, const ushort_t* __restrict__ WT1,
        const float* __restrict__ b0, const float* __restrict__ b1,
        void* __restrict__ Z0, void* __restrict__ Z1,
        const ushort_t* __restrict__ res) {
    const ushort_t* WT = blockIdx.z ? WT1 : WT0;
    const float* bias  = blockIdx.z ? b1 : b0;
    void* Z            = blockIdx.z ? Z1 : Z0;
    int w = threadIdx.x >> 6, lane = threadIdx.x & 63;
    int col = lane & 15, quad = lane >> 4;
    int m0 = blockIdx.x * 64 + w * 16, n0 = blockIdx.y * 64;
    f32x4_t acc[4];
#pragma unroll
    for (int t = 0; t < 4; ++t) acc[t] = (f32x4_t){0.f, 0.f, 0.f, 0.f};
    mm64<K>(X + (size_t)(m0 + col) * K + quad * 8,
            WT + (size_t)(n0 + col) * K + quad * 8, acc);
#pragma unroll
    for (int t = 0; t < 4; ++t)
#pragma unroll
        for (int rr = 0; rr < 4; ++rr) {
            int m = m0 + quad * 4 + rr;
            int n = n0 + t * 16 + col;
            float v = acc[t][rr] + bias[n];
            if (RES) v += bf16_bits_to_f(res[(size_t)m * 256 + n]);
            size_t idx = (size_t)m * 256 + n;
            if (OUTBF) ((ushort_t*)Z)[idx] = f_to_bf16_bits(v);
            else       ((float*)Z)[idx] = v;
        }
}

// ---------------------------------------------------------------------------
// MFMA flash attention (as round 4), ctx output now bf16.
// ---------------------------------------------------------------------------
__global__ __launch_bounds__(256) void k_attn_mfma(
        const ushort_t* __restrict__ q2b, const ushort_t* __restrict__ k2b,
        const ushort_t* __restrict__ v2b, const int* __restrict__ qb,
        const int* __restrict__ kst, const int* __restrict__ ken,
        ushort_t* __restrict__ ctxb) {
    int wave = threadIdx.x >> 6;
    int lane = threadIdx.x & 63;
    int qt = blockIdx.x >> 1;
    int h  = ((blockIdx.x & 1) << 2) | wave;
    int q0 = qt * 16;
    int col  = lane & 15;
    int quad = lane >> 4;

    int qq = q0 + col;
    int bq_ = qb[qq];
    int j0q = kst[bq_], j1q = ken[bq_];
    int jlo = j0q, jhi = j1q;
#pragma unroll
    for (int off = 1; off < 16; off <<= 1) {
        jlo = min(jlo, __shfl_xor(jlo, off, 64));
        jhi = max(jhi, __shfl_xor(jhi, off, 64));
    }

    bf16x8_t qf = *(const bf16x8_t*)(q2b + (size_t)qq * HID + h * DH + quad * 8);

    f32x4_t accO = {0.f, 0.f, 0.f, 0.f};
    float m_st = -1e30f, l_st = 0.f;

    for (int kt = jlo; kt < jhi; kt += 16) {
        int krow = kt + col;
        if (krow > NK - 1) krow = NK - 1;
        bf16x8_t kf = *(const bf16x8_t*)(k2b + (size_t)krow * HID + h * DH + quad * 8);
        ushort_t vr[4];
#pragma unroll
        for (int j = 0; j < 4; ++j) {
            int vrow = kt + quad * 4 + j;
            if (vrow > NK - 1) vrow = NK - 1;
            vr[j] = v2b[(size_t)vrow * HID + h * DH + col];
        }
        f32x4_t S = __builtin_amdgcn_mfma_f32_16x16x32_bf16(
            kf, qf, (f32x4_t){0.f, 0.f, 0.f, 0.f}, 0, 0, 0);

        float s[4];
        float mt = -3e38f;
#pragma unroll
        for (int r = 0; r < 4; ++r) {
            int kk = kt + quad * 4 + r;
            bool ok = (kk >= j0q) && (kk < j1q);
            s[r] = ok ? S[r] * ATT_SCALE : -3e38f;
            mt = fmaxf(mt, s[r]);
        }
        mt = fmaxf(mt, __shfl_xor(mt, 16, 64));
        mt = fmaxf(mt, __shfl_xor(mt, 32, 64));
        float m_new = fmaxf(m_st, mt);
        float alpha = __expf(m_st - m_new);
        float p[4], ps = 0.f;
#pragma unroll
        for (int r = 0; r < 4; ++r) { p[r] = __expf(s[r] - m_new); ps += p[r]; }
        ps += __shfl_xor(ps, 16, 64);
        ps += __shfl_xor(ps, 32, 64);
        l_st = l_st * alpha + ps;
        m_st = m_new;

        bf16x4_t pb, vb;
#pragma unroll
        for (int r = 0; r < 4; ++r) {
            pb[r] = (short)f_to_bf16_bits(p[r]);
            vb[r] = (short)vr[r];
        }
#pragma unroll
        for (int r = 0; r < 4; ++r) {
            float aq = __shfl(alpha, quad * 4 + r, 64);
            accO[r] *= aq;
        }
        accO = __builtin_amdgcn_mfma_f32_16x16x16bf16_1k(pb, vb, accO, 0, 0, 0);
    }

#pragma unroll
    for (int r = 0; r < 4; ++r) {
        float lq = __shfl(l_st, quad * 4 + r, 64);
        float o = (lq > 0.f) ? accO[r] / lq : 0.f;
        int qrow = q0 + quad * 4 + r;
        ctxb[(size_t)qrow * HID + h * DH + col] = f_to_bf16_bits(o);
    }
}

__global__ void k_ln(const float* __restrict__ X, const float* __restrict__ g,
                     const float* __restrict__ bb, void* __restrict__ out,
                     const int* __restrict__ flag) {
    __shared__ float red[8];
    int q = blockIdx.x, t = threadIdx.x;
    float x = X[(size_t)q * QD + t];
    float s = x, ss = x * x;
    for (int off = 32; off; off >>= 1) {
        s += __shfl_xor(s, off, 64);
        ss += __shfl_xor(ss, off, 64);
    }
    int w = t >> 6;
    if ((t & 63) == 0) { red[w] = s; red[4 + w] = ss; }
    __syncthreads();
    s = red[0] + red[1] + red[2] + red[3];
    ss = red[4] + red[5] + red[6] + red[7];
    float mu = s * (1.f / QD);
    float var = ss * (1.f / QD) - mu * mu;
    float inv = rsqrtf(var + LN_EPS);
    float y = (x - mu) * inv * g[t] + bb[t];
    size_t idx = (size_t)q * QD + t;
    if (*flag)
        ((__hip_bfloat16*)out)[idx] = (__hip_bfloat16)y;
    else
        ((float*)out)[idx] = y;
}

extern "C" void kernel_launch(void* const* d_in, const int* in_sizes, int n_in,
                              void* d_out, int out_size, void* d_ws, size_t ws_size,
                              hipStream_t stream) {
    const int* qbi = (const int*)d_in[16];
    const int* kbi = (const int*)d_in[17];

    float* w = (float*)d_ws;
    ushort_t* qnb  = (ushort_t*)(w + OFF_QNB);
    ushort_t* knb  = (ushort_t*)(w + OFF_KNB);
    ushort_t* q2b  = (ushort_t*)(w + OFF_Q2B);
    ushort_t* k2b  = (ushort_t*)(w + OFF_K2B);
    ushort_t* v2b  = (ushort_t*)(w + OFF_V2B);
    ushort_t* ctxb = (ushort_t*)(w + OFF_CTXB);
    float*    xres = w + OFF_XRES;
    ushort_t* wqb  = (ushort_t*)(w + OFF_WQB);
    ushort_t* wkb  = (ushort_t*)(w + OFF_WKB);
    ushort_t* wvb  = (ushort_t*)(w + OFF_WVB);
    ushort_t* winb = (ushort_t*)(w + OFF_WINB);
    ushort_t* mowb = (ushort_t*)(w + OFF_MOWB);
    ushort_t* wotb = (ushort_t*)(w + OFF_WOTB);
    ushort_t* wqt  = (ushort_t*)(w + OFF_WQT);
    ushort_t* wkt  = (ushort_t*)(w + OFF_WKT);
    ushort_t* wvt  = (ushort_t*)(w + OFF_WVT);
    ushort_t* wot  = (ushort_t*)(w + OFF_WOT);
    float* beffQ = w + OFF_BEFFQ;
    float* beffK = w + OFF_BEFFK;
    float* beffV = w + OFF_BEFFV;
    float* beffO = w + OFF_BEFFO;
    int* kst  = (int*)(w + OFF_KST);
    int* ken  = (int*)(w + OFF_KEN);
    int* flag = (int*)(w + OFF_FLAG);

    Ptrs16 ps;
    for (int i = 0; i < 16; ++i) ps.p[i] = d_in[i];

    k_detect<<<1, 256, 0, stream>>>((const ushort_t*)d_in[0], flag);
    k_cvt_all<<<(CVT_TOTAL + 255) / 256, 256, 0, stream>>>(ps, w, flag);
    k_ranges<<<NK / 256, 256, 0, stream>>>(kbi, kst, ken);
    k_fuse_gemm<<<72, 256, 0, stream>>>(winb, wqb, wkb, wvb, wotb, mowb,
                                        wqt, wkt, wvt, wot);
    k_bias<<<4, 256, 0, stream>>>(w + OFF_BQ, w + OFF_BK, w + OFF_BV,
                                  w + OFF_BINP, w + OFF_MOB, w + OFF_BO,
                                  winb, wotb, beffQ, beffK, beffV, beffO);
    k_gemm<256, 1, 0><<<dim3(NQ / 64, 4, 1), 256, 0, stream>>>(
        qnb, wqt, wqt, beffQ, beffQ, q2b, q2b, nullptr);
    k_gemm<320, 1, 0><<<dim3(NK / 64, 4, 2), 256, 0, stream>>>(
        knb, wkt, wvt, beffK, beffV, k2b, v2b, nullptr);
    k_attn_mfma<<<(NQ / 16) * 2, 256, 0, stream>>>(q2b, k2b, v2b, qbi, kst, ken,
                                                   ctxb);
    k_gemm<256, 0, 1><<<dim3(NQ / 64, 4, 1), 256, 0, stream>>>(
        ctxb, wot, wot, beffO, beffO, xres, xres, qnb);
    k_ln<<<NQ, 256, 0, stream>>>(xres, w + OFF_LNG, w + OFF_LNB, d_out, flag);
}